// Round 4
// baseline (100.600 us; speedup 1.0000x reference)
//
#include <hip/hip_runtime.h>
#include <math.h>

// ECE loss: per-row softmax-max confidence + argmax prediction, histogram over
// (pred_class, conf_bin) cells, ECE = sum|sum_conf - sum_acc| / N.
//
// Round-4 structure: WAVE-PRIVATE double-buffered pipeline, no barriers in the
// main loop (round-3 lost ~25% to stage->syncthreads->consume lockstep: zero
// loads in flight during every consume, barrier charges max HBM latency).
// Per wave, per iteration:
//   stage(next chunk): 4x global_load_lds(16B) + 1 label load  (= 5 VMEM)
//   s_waitcnt vmcnt(5)      <- counted wait: previous stage done, new 5 fly
//   consume(current buffer) <- oct-per-row from LDS, all in registers
// Stage addresses precomputed per-lane once (chunk-invariant). LDS row stride
// 27 float4 -> per-oct-phase conflict-free ds_read_b128.
//
// Assumes N % 8 == 0 (N = 1,000,000 here).
// Workspace (d_ws as float*): [0..NCELLS) sum_conf, [NCELLS..2*NCELLS) sum_acc.

constexpr int C  = 100;
constexpr int NB = 15;
constexpr int NCELLS = C * NB;            // 1500
constexpr int RPB  = 8;                   // rows per buffer (chunk)
constexpr int F4R  = 25;                  // float4 per row (payload)
constexpr int F4S  = 27;                  // padded LDS row stride (432 B)
constexpr int SLOTS = RPB * F4S;          // 216 LDS f4 slots per buffer
constexpr int WAVES = 4;                  // waves per block
constexpr int GRID_MAIN = 1024;           // 4 blocks/CU x 256 CU

__global__ void ece_zero(float* __restrict__ ws, int n) {
    int i = blockIdx.x * blockDim.x + threadIdx.x;
    if (i < n) ws[i] = 0.0f;
}

__device__ __forceinline__ void load_lds_16B(const void* gsrc, void* ldst) {
    __builtin_amdgcn_global_load_lds(
        (const __attribute__((address_space(1))) void*)gsrc,
        (__attribute__((address_space(3))) void*)ldst, 16, 0, 0);
}

__global__ __launch_bounds__(256)
void ece_main(const float* __restrict__ logits,
              const int* __restrict__ labels,
              int nchunk, float* __restrict__ cellsums) {
    __shared__ float4 stage[WAVES][2][SLOTS];   // 4*2*216*16 = 27648 B
    __shared__ float  hist[2 * NCELLS];         // 12000 B -> 39.6 KB, 4 blk/CU

    for (int i = threadIdx.x; i < 2 * NCELLS; i += blockDim.x) hist[i] = 0.0f;
    __syncthreads();

    const int wid   = threadIdx.x >> 6;
    const int lane  = threadIdx.x & 63;
    const int gwave = blockIdx.x * WAVES + wid;
    const int gstr  = gridDim.x * WAVES;
    const float4* logits4 = reinterpret_cast<const float4*>(logits);
    constexpr float LOG2E = 1.4426950408889634f;

    // Per-lane stage source offsets (chunk-invariant). Slot s = i*64+lane maps
    // to (row r = s/27, col c = s%27); pad cols 25,26 clamp to 24 (duplicate
    // read of an already-fetched line -> zero extra HBM, branchless).
    int offs[4];
    #pragma unroll
    for (int i = 0; i < 4; ++i) {
        int s = i * 64 + lane;
        int r = s / F4S, c = s - r * F4S;
        if (c > F4R - 1) c = F4R - 1;
        if (s >= SLOTS) { r = 0; c = 0; }   // lanes masked off in instr 3
        offs[i] = r * F4R + c;
    }
    const bool act3 = lane < (SLOTS - 192);  // 24 active lanes in instr 3

    float4* buf0 = &stage[wid][0][0];
    float4* buf1 = &stage[wid][1][0];

    const int o = lane >> 3;   // oct id = row within chunk
    const int j = lane & 7;    // lane within oct

#define DO_STAGE(BUF, CHUNK, LABDST)                                          \
    {                                                                         \
        const float4* src_ = logits4 + (size_t)(CHUNK) * (RPB * F4R);         \
        LABDST = labels[(CHUNK) * RPB + o];                                   \
        char* lb_ = (char*)(BUF);                                             \
        load_lds_16B(src_ + offs[0], lb_);                                    \
        load_lds_16B(src_ + offs[1], lb_ + 64 * 16);                          \
        load_lds_16B(src_ + offs[2], lb_ + 128 * 16);                         \
        if (act3) load_lds_16B(src_ + offs[3], lb_ + 192 * 16);               \
    }

    int lab_cur = 0, lab_nxt = 0;
    int k = gwave;
    int cur = 0;
    if (k < nchunk) DO_STAGE(buf0, k, lab_cur);

    for (; k < nchunk; k += gstr) {
        const int kn = k + gstr;          // wave-uniform
        if (kn < nchunk) {
            DO_STAGE(cur ? buf1 : buf0 + SLOTS /*== buf1? no: see swap*/, 0, lab_nxt);
        }
        // NOTE: macro above can't pick buffer via ternary cleanly; real code below.
        (void)0;
        break; // placeholder never reached; loop rewritten below
    }
#undef DO_STAGE

    // ---- real pipeline loop (explicit, no macro buffer-selection tricks) ----
    {
        float4* bufs[2] = { buf0, buf1 };
        lab_cur = 0; lab_nxt = 0; cur = 0;
        k = gwave;
        if (k < nchunk) {
            const float4* src = logits4 + (size_t)k * (RPB * F4R);
            lab_cur = labels[k * RPB + o];
            char* lb = (char*)bufs[0];
            load_lds_16B(src + offs[0], lb);
            load_lds_16B(src + offs[1], lb + 64 * 16);
            load_lds_16B(src + offs[2], lb + 128 * 16);
            if (act3) load_lds_16B(src + offs[3], lb + 192 * 16);
        }

        for (; k < nchunk; k += gstr) {
            const int kn = k + gstr;
            if (kn < nchunk) {
                const float4* src = logits4 + (size_t)kn * (RPB * F4R);
                lab_nxt = labels[kn * RPB + o];
                char* lb = (char*)bufs[cur ^ 1];
                load_lds_16B(src + offs[0], lb);
                load_lds_16B(src + offs[1], lb + 64 * 16);
                load_lds_16B(src + offs[2], lb + 128 * 16);
                if (act3) load_lds_16B(src + offs[3], lb + 192 * 16);
                asm volatile("s_waitcnt vmcnt(5)" ::: "memory");
            } else {
                asm volatile("s_waitcnt vmcnt(0)" ::: "memory");
            }
            __builtin_amdgcn_sched_barrier(0);

            // ---- consume bufs[cur]: oct-per-row ----
            const float4* rp = bufs[cur] + o * F4S;
            float4 v0 = rp[j], v1 = rp[j + 8], v2 = rp[j + 16];
            float4 v3;
            const bool tail = (j == 0);
            if (tail) v3 = rp[24];

            // per-lane max + first-occurrence argmax (ascending elem order)
            float m = v0.x; int am = 4 * j;
            if (v0.y > m) { m = v0.y; am = 4 * j + 1; }
            if (v0.z > m) { m = v0.z; am = 4 * j + 2; }
            if (v0.w > m) { m = v0.w; am = 4 * j + 3; }
            if (v1.x > m) { m = v1.x; am = 32 + 4 * j; }
            if (v1.y > m) { m = v1.y; am = 32 + 4 * j + 1; }
            if (v1.z > m) { m = v1.z; am = 32 + 4 * j + 2; }
            if (v1.w > m) { m = v1.w; am = 32 + 4 * j + 3; }
            if (v2.x > m) { m = v2.x; am = 64 + 4 * j; }
            if (v2.y > m) { m = v2.y; am = 64 + 4 * j + 1; }
            if (v2.z > m) { m = v2.z; am = 64 + 4 * j + 2; }
            if (v2.w > m) { m = v2.w; am = 64 + 4 * j + 3; }
            if (tail) {
                if (v3.x > m) { m = v3.x; am = 96; }
                if (v3.y > m) { m = v3.y; am = 97; }
                if (v3.z > m) { m = v3.z; am = 98; }
                if (v3.w > m) { m = v3.w; am = 99; }
            }
            #pragma unroll
            for (int off = 1; off < 8; off <<= 1) {
                float om  = __shfl_xor(m, off, 64);
                int   oam = __shfl_xor(am, off, 64);
                if (om > m || (om == m && oam < am)) { m = om; am = oam; }
            }

            // sum exp(x-m) = exp2(x*log2e - m*log2e)
            const float ml = m * LOG2E;
            float s = exp2f(__fmaf_rn(v0.x, LOG2E, -ml))
                    + exp2f(__fmaf_rn(v0.y, LOG2E, -ml))
                    + exp2f(__fmaf_rn(v0.z, LOG2E, -ml))
                    + exp2f(__fmaf_rn(v0.w, LOG2E, -ml));
            s += exp2f(__fmaf_rn(v1.x, LOG2E, -ml))
               + exp2f(__fmaf_rn(v1.y, LOG2E, -ml))
               + exp2f(__fmaf_rn(v1.z, LOG2E, -ml))
               + exp2f(__fmaf_rn(v1.w, LOG2E, -ml));
            s += exp2f(__fmaf_rn(v2.x, LOG2E, -ml))
               + exp2f(__fmaf_rn(v2.y, LOG2E, -ml))
               + exp2f(__fmaf_rn(v2.z, LOG2E, -ml))
               + exp2f(__fmaf_rn(v2.w, LOG2E, -ml));
            if (tail) {
                s += exp2f(__fmaf_rn(v3.x, LOG2E, -ml))
                   + exp2f(__fmaf_rn(v3.y, LOG2E, -ml))
                   + exp2f(__fmaf_rn(v3.z, LOG2E, -ml))
                   + exp2f(__fmaf_rn(v3.w, LOG2E, -ml));
            }
            #pragma unroll
            for (int off = 1; off < 8; off <<= 1) s += __shfl_xor(s, off, 64);

            if (tail) {
                float conf = 1.0f / s;
                int b = (int)ceilf(conf * (float)NB) - 1;
                b = b < 0 ? 0 : (b > NB - 1 ? NB - 1 : b);
                int cell = am * NB + b;
                atomicAdd(&hist[cell], conf);
                if (lab_cur == am) atomicAdd(&hist[NCELLS + cell], 1.0f);
            }

            // all ds_reads of bufs[cur] retired before next-iter overwrite
            asm volatile("s_waitcnt lgkmcnt(0)" ::: "memory");
            lab_cur = lab_nxt;
            cur ^= 1;
        }
    }

    __syncthreads();
    for (int i = threadIdx.x; i < 2 * NCELLS; i += blockDim.x) {
        float v = hist[i];
        if (v != 0.0f) atomicAdd(&cellsums[i], v);
    }
}

__global__ void ece_final(const float* __restrict__ cellsums,
                          float invN, float* __restrict__ out) {
    __shared__ float red[256];
    float t = 0.0f;
    for (int i = threadIdx.x; i < NCELLS; i += blockDim.x)
        t += fabsf(cellsums[i] - cellsums[NCELLS + i]);
    red[threadIdx.x] = t;
    __syncthreads();
    for (int w = 128; w > 0; w >>= 1) {
        if (threadIdx.x < w) red[threadIdx.x] += red[threadIdx.x + w];
        __syncthreads();
    }
    if (threadIdx.x == 0) out[0] = red[0] * invN;
}

extern "C" void kernel_launch(void* const* d_in, const int* in_sizes, int n_in,
                              void* d_out, int out_size, void* d_ws, size_t ws_size,
                              hipStream_t stream) {
    const float* logits = (const float*)d_in[0];
    const int*   labels = (const int*)d_in[1];

    const int N = in_sizes[1];          // 1,000,000 (divisible by RPB=8)
    const int nchunk = N / RPB;         // 125,000

    float* cellsums = (float*)d_ws;
    float* out = (float*)d_out;

    // 1) zero global cell accumulators (harness poisons ws, never re-zeroes)
    {
        int n = 2 * NCELLS;
        ece_zero<<<(n + 255) / 256, 256, 0, stream>>>(cellsums, n);
    }

    // 2) main pass: wave-private double-buffered pipeline
    ece_main<<<GRID_MAIN, 256, 0, stream>>>(logits, labels, nchunk, cellsums);

    // 3) finalize
    ece_final<<<1, 256, 0, stream>>>(cellsums, 1.0f / (float)N, out);
}